// Round 12
// baseline (361.285 us; speedup 1.0000x reference)
//
#include <hip/hip_runtime.h>
#include <hip/hip_bf16.h>
#include <math.h>

// Problem constants (B,T,E)=(4,2048,512), H=8, D=64, HID=H*E=4096.
#define Bsz 4
#define Tt 2048
#define Ee 512
#define Hh 8
#define Dd 64
#define HIDs 4096
#define Mrows (Bsz * Tt)   // 8192 token rows

typedef __attribute__((ext_vector_type(8))) short short8;   // 8 bf16 (4 VGPRs)
typedef __attribute__((ext_vector_type(4))) float f32x4;    // MFMA accumulator

#define AS1 __attribute__((address_space(1)))
#define AS3 __attribute__((address_space(3)))

__device__ __forceinline__ unsigned short f2bfu(float f) {   // RNE float->bf16 bits
    unsigned u = __float_as_uint(f);
    return (unsigned short)((u + 0x7fffu + ((u >> 16) & 1u)) >> 16);
}
__device__ __forceinline__ unsigned short truncbf(float f) { // truncating (P only)
    return (unsigned short)(__float_as_uint(f) >> 16);
}

// ---------------------------------------------------------------------------
// LN body (shared by startup + LN2 kernels).
__device__ __forceinline__ void ln_body(const float* __restrict__ x,
        const float* __restrict__ g, const float* __restrict__ b,
        const float* __restrict__ addb,
        float* __restrict__ out_f, __hip_bfloat16* __restrict__ out_bf,
        int row) {
    int tid = threadIdx.x;
    const float* xr = x + (size_t)row * Ee;
    float v0 = xr[tid];
    float v1 = xr[tid + 256];
    float s = v0 + v1;
    float sq = v0 * v0 + v1 * v1;
#pragma unroll
    for (int off = 32; off > 0; off >>= 1) {
        s  += __shfl_xor(s, off, 64);
        sq += __shfl_xor(sq, off, 64);
    }
    __shared__ float ls[4], lq[4];
    int wid = tid >> 6, lane = tid & 63;
    if (lane == 0) { ls[wid] = s; lq[wid] = sq; }
    __syncthreads();
    s  = ls[0] + ls[1] + ls[2] + ls[3];
    sq = lq[0] + lq[1] + lq[2] + lq[3];
    float mean = s * (1.0f / Ee);
    float var  = sq * (1.0f / Ee) - mean * mean;   // biased var, like jnp.var
    float rstd = rsqrtf(var + 1e-5f);
    float o0 = (v0 - mean) * rstd * g[tid]       + b[tid];
    float o1 = (v1 - mean) * rstd * g[tid + 256] + b[tid + 256];
    float* orow = out_f + (size_t)row * Ee;
    orow[tid]       = o0 + addb[tid];
    orow[tid + 256] = o1 + addb[tid + 256];
    __hip_bfloat16* brow = out_bf + (size_t)row * Ee;
    brow[tid]       = __float2bfloat16(o0);
    brow[tid + 256] = __float2bfloat16(o1);
}

__global__ __launch_bounds__(256) void ln_kernel(const float* __restrict__ x,
        const float* __restrict__ g, const float* __restrict__ b,
        const float* __restrict__ addb,
        float* __restrict__ out_f, __hip_bfloat16* __restrict__ out_bf) {
    ln_body(x, g, b, addb, out_f, out_bf, blockIdx.x);
}

// ---------------------------------------------------------------------------
// Startup: LN1 (blocks [0,8192)) + all weight repacks ([8192,9472)) fused.
//   repack ranges: [0,192) qkv (Wq pre-scaled by T^-0.5*log2e), [192,256) Wo,
//   [256,768) W1, [768,1280) W2.
__device__ __forceinline__ void tr_tile(const float* __restrict__ in,
        __hip_bfloat16* __restrict__ outp, int R, int C, int c0, int r0) {
    __shared__ float tile[64][65];
    int tc = threadIdx.x & 63, tg = threadIdx.x >> 6;
#pragma unroll
    for (int i = 0; i < 16; ++i) {
        int r = tg * 16 + i;
        tile[r][tc] = in[(size_t)(r0 + r) * C + c0 + tc];
    }
    __syncthreads();
#pragma unroll
    for (int i = 0; i < 16; ++i) {
        int cc = tg * 16 + i;
        outp[(size_t)(c0 + cc) * R + r0 + tc] = __float2bfloat16(tile[tc][cc]);
    }
}
__global__ __launch_bounds__(256) void startup_kernel(
        const float* __restrict__ x, const float* __restrict__ g1,
        const float* __restrict__ be1, const float* __restrict__ bo,
        float* __restrict__ xn, __hip_bfloat16* __restrict__ xn_bf,
        const float* __restrict__ Wq, const float* __restrict__ Wk,
        const float* __restrict__ Wv, const float* __restrict__ Wo,
        const float* __restrict__ W1, const float* __restrict__ W2,
        __hip_bfloat16* __restrict__ bqT, __hip_bfloat16* __restrict__ woT,
        __hip_bfloat16* __restrict__ w1T, __hip_bfloat16* __restrict__ w2T) {
    if (blockIdx.x < Mrows) {
        ln_body(x, g1, be1, bo, xn, xn_bf, blockIdx.x);
        return;
    }
    int blk = blockIdx.x - Mrows;
    if (blk < 192) {                 // qkv: p*64 + h*8 + et
        int p = blk >> 6, h = (blk >> 3) & 7, et = blk & 7;
        const float* W = (p == 0) ? Wq : ((p == 1) ? Wk : Wv);
        float sc = (p == 0) ? 0.022097086912079608f * 1.4426950408889634f : 1.0f;
        __shared__ float tile[64][65];
        int td = threadIdx.x & 63, tg = threadIdx.x >> 6;
#pragma unroll
        for (int i = 0; i < 16; ++i) {
            int e = tg * 16 + i;
            tile[e][td] = W[((size_t)h * Ee + et * 64 + e) * Dd + td] * sc;
        }
        __syncthreads();
#pragma unroll
        for (int i = 0; i < 16; ++i) {
            int d = tg * 16 + i;
            bqT[((size_t)(p * 512 + h * 64 + d)) * Ee + et * 64 + td] =
                __float2bfloat16(tile[td][d]);
        }
    } else if (blk < 256) {
        int t = blk - 192;           // 8x8
        tr_tile(Wo, woT, 512, 512, (t & 7) * 64, (t >> 3) * 64);
    } else if (blk < 768) {
        int t = blk - 256;           // 64x8
        tr_tile(W1, w1T, 512, HIDs, (t & 63) * 64, (t >> 6) * 64);
    } else {
        int t = blk - 768;           // 8x64
        tr_tile(W2, w2T, HIDs, 512, (t & 7) * 64, (t >> 3) * 64);
    }
}

// ---------------------------------------------------------------------------
// bf16 MFMA GEMM (QKV): 128x128 tile, BK=64 two-panel LDS, XCD swizzle.
// Epilogue: per-wave LDS transpose (no barrier; same-wave DS in order),
// then uint4 coalesced bf16 stores.
__global__ __launch_bounds__(256) void mfma_gemm(
        const __hip_bfloat16* __restrict__ A, int lda,
        const __hip_bfloat16* __restrict__ B, int ldb,
        __hip_bfloat16* __restrict__ Cb, int ldc, int K, int nx) {
    __shared__ __hip_bfloat16 S[16384];           // As 8192 | Bs 8192 (32 KB)
    __hip_bfloat16* As = S;
    __hip_bfloat16* Bs = S + 8192;
    int tid = threadIdx.x;
    int lane = tid & 63, wave = tid >> 6;
    int wm = wave >> 1, wn = wave & 1;
    int L = blockIdx.x;
    int slots = (int)gridDim.x >> 3;
    int v = (L & 7) * slots + (L >> 3);
    int bx = v % nx, by = v / nx;
    int row0 = by * 128, col0 = bx * 128;
    f32x4 acc[4][4];
#pragma unroll
    for (int i = 0; i < 4; ++i)
#pragma unroll
        for (int j = 0; j < 4; ++j) acc[i][j] = (f32x4){0.f, 0.f, 0.f, 0.f};

    int fr = lane & 15;
    int kq = (lane >> 4) << 3;

    for (int k0 = 0; k0 < K; k0 += 64) {
        __syncthreads();
#pragma unroll
        for (int j = 0; j < 4; ++j) {
            int c  = j * 256 + tid;
            int cb = j * 256 + wave * 64;
            int p  = c >> 9, cp = c & 511;
            int r  = cp >> 2, kg = (cp & 3) << 3;
            int ko = k0 + p * 32 + kg;
            __builtin_amdgcn_global_load_lds(
                (const AS1 void*)(A + (size_t)(row0 + r) * lda + ko),
                (AS3 void*)(As + cb * 8), 16, 0, 0);
            __builtin_amdgcn_global_load_lds(
                (const AS1 void*)(B + (size_t)(col0 + r) * ldb + ko),
                (AS3 void*)(Bs + cb * 8), 16, 0, 0);
        }
        __syncthreads();
#pragma unroll
        for (int ks = 0; ks < 2; ++ks) {
            short8 afr[4], bfr[4];
#pragma unroll
            for (int i = 0; i < 4; ++i) {
                afr[i] = *(const short8*)(As + ks * 4096 + (wm * 64 + i * 16 + fr) * 32 + kq);
                bfr[i] = *(const short8*)(Bs + ks * 4096 + (wn * 64 + i * 16 + fr) * 32 + kq);
            }
#pragma unroll
            for (int i = 0; i < 4; ++i)
#pragma unroll
                for (int j = 0; j < 4; ++j)
                    acc[i][j] = __builtin_amdgcn_mfma_f32_16x16x32_bf16(afr[i], bfr[j], acc[i][j], 0, 0, 0);
        }
    }
    // ---- epilogue: per-wave LDS transpose -> uint4 stores (stride 72, 16B-aligned)
    __syncthreads();                  // staging LDS reads complete; reuse as Ew
    unsigned short* Ew = (unsigned short*)S + wave * 1152;   // 16 x 72
    const __hip_bfloat16* Er = (const __hip_bfloat16*)Ew;
    int rq = (lane >> 4) << 2;
    int rr = lane >> 2, cb2 = (lane & 3) * 16;
#pragma unroll
    for (int i = 0; i < 4; ++i) {
#pragma unroll
        for (int j = 0; j < 4; ++j)
#pragma unroll
            for (int gi = 0; gi < 4; ++gi)
                Ew[(rq + gi) * 72 + j * 16 + fr] = f2bfu(acc[i][j][gi]);
        uint4 v0 = *(const uint4*)(Er + rr * 72 + cb2);
        uint4 v1 = *(const uint4*)(Er + rr * 72 + cb2 + 8);
        size_t rg = (size_t)(row0 + wm * 64 + i * 16 + rr) * ldc + col0 + wn * 64 + cb2;
        *(uint4*)(Cb + rg)     = v0;
        *(uint4*)(Cb + rg + 8) = v1;
    }
}

// ---------------------------------------------------------------------------
// bf16 MFMA GEMM, 128x64 tile, full K (no split, no atomics). 4 waves x
// (32m x 64n). Epilogue: Cf[ci] += acc (plain RMW; fp32 stores already form
// full 64B lines per 16-lane group). Used for Wo (K=512), FFN2 (K=4096).
__global__ __launch_bounds__(256) void mfma_gemm_n64(
        const __hip_bfloat16* __restrict__ A, int lda,
        const __hip_bfloat16* __restrict__ B, int ldb,
        float* __restrict__ Cf, int ldc, int K, int nx) {
    __shared__ __hip_bfloat16 As[2 * 128 * 32];   // 16 KB
    __shared__ __hip_bfloat16 Bs[2 * 64 * 32];    //  8 KB
    int tid = threadIdx.x;
    int lane = tid & 63, wave = tid >> 6;
    int L = blockIdx.x;
    int slots = (int)gridDim.x >> 3;
    int v = (L & 7) * slots + (L >> 3);
    int bx = v % nx, by = v / nx;
    int row0 = by * 128, col0 = bx * 64;
    f32x4 acc[2][4];
#pragma unroll
    for (int i = 0; i < 2; ++i)
#pragma unroll
        for (int j = 0; j < 4; ++j) acc[i][j] = (f32x4){0.f, 0.f, 0.f, 0.f};

    int fr = lane & 15;
    int kq = (lane >> 4) << 3;

    for (int k0 = 0; k0 < K; k0 += 64) {
        __syncthreads();
#pragma unroll
        for (int j = 0; j < 4; ++j) {
            int c  = j * 256 + tid;
            int cb = j * 256 + wave * 64;
            int p  = c >> 9, cp = c & 511;
            int r  = cp >> 2, kg = (cp & 3) << 3;
            __builtin_amdgcn_global_load_lds(
                (const AS1 void*)(A + (size_t)(row0 + r) * lda + k0 + p * 32 + kg),
                (AS3 void*)(As + cb * 8), 16, 0, 0);
        }
#pragma unroll
        for (int j = 0; j < 2; ++j) {
            int c  = j * 256 + tid;
            int cb = j * 256 + wave * 64;
            int p  = c >> 8, cp = c & 255;
            int r  = cp >> 2, kg = (cp & 3) << 3;
            __builtin_amdgcn_global_load_lds(
                (const AS1 void*)(B + (size_t)(col0 + r) * ldb + k0 + p * 32 + kg),
                (AS3 void*)(Bs + cb * 8), 16, 0, 0);
        }
        __syncthreads();
#pragma unroll
        for (int ks = 0; ks < 2; ++ks) {
            short8 afr[2], bfr[4];
#pragma unroll
            for (int i = 0; i < 2; ++i)
                afr[i] = *(const short8*)(As + ks * 4096 + (wave * 32 + i * 16 + fr) * 32 + kq);
#pragma unroll
            for (int j = 0; j < 4; ++j)
                bfr[j] = *(const short8*)(Bs + ks * 2048 + (j * 16 + fr) * 32 + kq);
#pragma unroll
            for (int i = 0; i < 2; ++i)
#pragma unroll
                for (int j = 0; j < 4; ++j)
                    acc[i][j] = __builtin_amdgcn_mfma_f32_16x16x32_bf16(afr[i], bfr[j], acc[i][j], 0, 0, 0);
        }
    }
    int rq = (lane >> 4) << 2;
#pragma unroll
    for (int i = 0; i < 2; ++i)
#pragma unroll
        for (int j = 0; j < 4; ++j)
#pragma unroll
            for (int gidx = 0; gidx < 4; ++gidx) {
                int r = row0 + wave * 32 + i * 16 + rq + gidx;
                int c = col0 + j * 16 + fr;
                Cf[(size_t)r * ldc + c] += acc[i][j][gidx];
            }
}

// ---------------------------------------------------------------------------
// bf16 MFMA GEMM, 256x128 tile (FFN1): BK=32 SINGLE buffer -> 24 KB LDS ->
// grid 1024 = 4 blocks/CU ALL co-resident (inter-block overlap hides the
// barrier drains; pipelining within a block was measured neutral). 2D XCD
// supertile swizzle (grid must be 32x32). Epilogue: per-wave LDS transpose,
// relu+bias, uint4 stores.
__global__ __launch_bounds__(256) void mfma_gemm256(
        const __hip_bfloat16* __restrict__ A, int lda,
        const __hip_bfloat16* __restrict__ B, int ldb,
        __hip_bfloat16* __restrict__ Cb, int ldc, int K,
        const float* __restrict__ bias) {
    __shared__ __hip_bfloat16 S[12288];           // As 8192 | Bs 4096 (24 KB)
    __hip_bfloat16* As = S;
    __hip_bfloat16* Bs = S + 8192;
    int tid = threadIdx.x;
    int lane = tid & 63, wave = tid >> 6;
    int L = blockIdx.x;
    int k8 = L & 7, sub = L >> 3;     // XCD id (round-robin), slot in XCD
    int sr = k8 >> 1, sc = k8 & 1;    // supertile grid 4x2
    int by = sr * 8 + (sub >> 4);
    int bx = sc * 16 + (sub & 15);
    int row0 = by * 256, col0 = bx * 128;
    f32x4 acc[4][8];
#pragma unroll
    for (int i = 0; i < 4; ++i)
#pragma unroll
        for (int j = 0; j < 8; ++j) acc[i][j] = (f32x4){0.f, 0.f, 0.f, 0.f};

    int fr = lane & 15;
    int kq = (lane >> 4) << 3;

    for (int k0 = 0; k0 < K; k0 += 32) {
        __syncthreads();
        // A: 1024 16B chunks (4/thread), row-major [r][32]
#pragma unroll
        for (int j = 0; j < 4; ++j) {
            int c  = j * 256 + tid;
            int cb = j * 256 + wave * 64;
            int r = c >> 2, kg = (c & 3) << 3;
            __builtin_amdgcn_global_load_lds(
                (const AS1 void*)(A + (size_t)(row0 + r) * lda + k0 + kg),
                (AS3 void*)(As + cb * 8), 16, 0, 0);
        }
        // B: 512 chunks (2/thread)
#pragma unroll
        for (int j = 0; j < 2; ++j) {
            int c  = j * 256 + tid;
            int cb = j * 256 + wave * 64;
            int r = c >> 2, kg = (c & 3) << 3;
            __builtin_amdgcn_global_load_lds(
                (const AS1 void*)(B + (size_t)(col0 + r) * ldb + k0 + kg),
                (AS3 void*)(Bs + cb * 8), 16, 0, 0);
        }
        __syncthreads();
        short8 afr[4], bfr[8];
#pragma unroll
        for (int i = 0; i < 4; ++i)
            afr[i] = *(const short8*)(As + (wave * 64 + i * 16 + fr) * 32 + kq);
#pragma unroll
        for (int j = 0; j < 8; ++j)
            bfr[j] = *(const short8*)(Bs + (j * 16 + fr) * 32 + kq);
#pragma unroll
        for (int i = 0; i < 4; ++i)
#pragma unroll
            for (int j = 0; j < 8; ++j)
                acc[i][j] = __builtin_amdgcn_mfma_f32_16x16x32_bf16(afr[i], bfr[j], acc[i][j], 0, 0, 0);
    }
    // ---- epilogue: bias+relu -> per-wave LDS transpose -> uint4 stores
    __syncthreads();                  // staging reads complete; reuse S as Ew
    float bv[8];
#pragma unroll
    for (int j = 0; j < 8; ++j) bv[j] = bias[col0 + j * 16 + fr];
    unsigned short* Ew = (unsigned short*)S + wave * 2176;   // 16 x 136
    const __hip_bfloat16* Er = (const __hip_bfloat16*)Ew;
    int rq = (lane >> 4) << 2;
    int rr = lane >> 2, cb2 = (lane & 3) * 32;
#pragma unroll
    for (int i = 0; i < 4; ++i) {
#pragma unroll
        for (int j = 0; j < 8; ++j)
#pragma unroll
            for (int gi = 0; gi < 4; ++gi) {
                float t = acc[i][j][gi] + bv[j];
                Ew[(rq + gi) * 136 + j * 16 + fr] = f2bfu(t > 0.f ? t : 0.f);
            }
        size_t rg = (size_t)(row0 + wave * 64 + i * 16 + rr) * ldc + col0 + cb2;
#pragma unroll
        for (int u = 0; u < 4; ++u)
            *(uint4*)(Cb + rg + u * 8) = *(const uint4*)(Er + rr * 136 + cb2 + u * 8);
    }
}

// ---------------------------------------------------------------------------
// MFMA flash attention, no-max softmax, register-prefetch pipeline.
// One block = 128 Q rows of one (b,h); 8 waves x 16 rows. Q pre-scaled
// (T^-0.5*log2e folded into Wq at repack).
__global__ __launch_bounds__(512) void attn_mfma(const __hip_bfloat16* __restrict__ qkvb,
        __hip_bfloat16* __restrict__ ob) {
    __shared__ __hip_bfloat16 KsS[64 * 72];     // K tile [s][d], pad 72
    __shared__ __hip_bfloat16 VtS[64 * 72];     // V^T tile [d][s], pad 72
    __shared__ __hip_bfloat16 PsS[8 * 16 * 72]; // P [wave][q][s] bf16; Q overlays
    __hip_bfloat16* Qs = PsS;                   // Q staging [128 q][72]

    const unsigned short* q16 = (const unsigned short*)qkvb;
    int tid  = threadIdx.x;
    int lane = tid & 63, wave = tid >> 6;
    int g = lane >> 4, c = lane & 15;
    int blk = blockIdx.x;
    int qb  = 15 - (blk >> 5);                // global heavy-first
    int bh  = blk & 31;
    int b = bh >> 3, h = bh & 7;
    int base = qb * 128;
    size_t tokbase = (size_t)b * Tt;
    int qoff = h * 64, koff = 512 + h * 64, voff = 1024 + h * 64;

    {   // stage Q (already scaled) into Qs[q][72], 128 rows
        int q = tid >> 2, dg = (tid & 3) * 16;
        const unsigned short* src = q16 + (tokbase + base + q) * 1536 + qoff + dg;
        uint4 a  = *(const uint4*)src;
        uint4 b4 = *(const uint4*)(src + 8);
        *(uint4*)(Qs + q * 72 + dg)     = a;
        *(uint4*)(Qs + q * 72 + dg + 8) = b4;
    }
    __syncthreads();
    short8 aq[2];
    aq[0] = *(const short8*)(Qs + (wave * 16 + c) * 72 + g * 8);
    aq[1] = *(const short8*)(Qs + (wave * 16 + c) * 72 + 32 + g * 8);

    short8 ones;
#pragma unroll
    for (int i = 0; i < 8; ++i) ones[i] = (short)0x3F80;   // bf16 1.0

    f32x4 acc[4];
#pragma unroll
    for (int dt = 0; dt < 4; ++dt) acc[dt] = (f32x4){0.f, 0.f, 0.f, 0.f};
    f32x4 accL = (f32x4){0.f, 0.f, 0.f, 0.f};   // row-sums of P
    __hip_bfloat16* Psw = PsS + wave * (16 * 72);
    unsigned short* Psw16 = (unsigned short*)Psw;

    // prefetch lane roles
    int s_k = tid >> 3, dg_k = (tid & 7) * 8;       // K: 1 uint4 per thread
    int sp = (tid & 31) * 2, dg4 = (tid >> 5) * 4;  // V: 2 uint2 per thread
    uint4 kreg; uint2 va, vb;
    {   // prologue: load tile 0
        kreg = *(const uint4*)(q16 + (tokbase + s_k) * 1536 + koff + dg_k);
        const unsigned short* r0p = q16 + (tokbase + sp) * 1536 + voff + dg4;
        va = *(const uint2*)r0p;
        vb = *(const uint2*)(r0p + 1536);
    }

    int tmax = 2 * qb + 1;
    for (int tile = 0; tile <= tmax; ++tile) {
        __syncthreads();                      // prior tile's LDS reads done
        *(uint4*)(KsS + s_k * 72 + dg_k) = kreg;
        {
            unsigned a0[2] = {va.x, va.y};
            unsigned b0[2] = {vb.x, vb.y};
#pragma unroll
            for (int i = 0; i < 2; ++i) {
                unsigned p0 = (a0[i] & 0xffffu) | (b0[i] << 16);
                unsigned p1 = (a0[i] >> 16) | (b0[i] & 0xffff0000u);
                *(unsigned*)(VtS + (dg4 + 2 * i) * 72 + sp)     = p0;
                *(unsigned*)(VtS + (dg4 + 2 * i + 1) * 72 + sp) = p1;
            }
        }
        __syncthreads();
        if (tile < tmax) {                    // prefetch tile+1 under compute
            int s1 = (tile + 1) * 64;
            kreg = *(const uint4*)(q16 + (tokbase + s1 + s_k) * 1536 + koff + dg_k);
            const unsigned short* r0p = q16 + (tokbase + s1 + sp) * 1536 + voff + dg4;
            va = *(const uint2*)r0p;
            vb = *(const uint2*)(r0p + 1536);
        }
        if (tile == tmax && wave < 4) continue;   // fully masked for waves 0-3
        f32x4 Sc[4];
#pragma unroll
        for (int st = 0; st < 4; ++st) Sc[st] = (f32x4){0.f, 0.f, 0.f, 0.f};
#pragma unroll
        for (int ks = 0; ks < 2; ++ks)
#pragma unroll
            for (int st = 0; st < 4; ++st) {
                short8 bk = *(const short8*)(KsS + (st * 16 + c) * 72 + ks * 32 + g * 8);
                Sc[st] = __builtin_amdgcn_mfma_f32_16x16x32_bf16(aq[ks], bk, Sc[st], 0, 0, 0);
            }
        if (tile >= 2 * qb) {                 // diagonal-straddling tiles
            int s0 = tile * 64;
            int qg = base + wave * 16 + g * 4;
#pragma unroll
            for (int st = 0; st < 4; ++st) {
                int sg = s0 + st * 16 + c;
#pragma unroll
                for (int r = 0; r < 4; ++r)
                    if (sg > qg + r) Sc[st][r] = -1e30f;
            }
        }
#pragma unroll
        for (int st = 0; st < 4; ++st)
#pragma unroll
            for (int r = 0; r < 4; ++r)
                Psw16[(g * 4 + r) * 72 + st * 16 + c] =
                    truncbf(__builtin_amdgcn_exp2f(Sc[st][r]));
#pragma unroll
        for (int ks = 0; ks < 2; ++ks) {
            short8 ap = *(const short8*)(Psw + c * 72 + ks * 32 + g * 8);
            accL = __builtin_amdgcn_mfma_f32_16x16x32_bf16(ap, ones, accL, 0, 0, 0);
#pragma unroll
            for (int dt = 0; dt < 4; ++dt) {
                short8 bv = *(const short8*)(VtS + (dt * 16 + c) * 72 + ks * 32 + g * 8);
                acc[dt] = __builtin_amdgcn_mfma_f32_16x16x32_bf16(ap, bv, acc[dt], 0, 0, 0);
            }
        }
    }
    float rl[4];
#pragma unroll
    for (int r = 0; r < 4; ++r) rl[r] = 1.0f / accL[r];
#pragma unroll
    for (int dt = 0; dt < 4; ++dt)
#pragma unroll
        for (int r = 0; r < 4; ++r) {
            int row = base + wave * 16 + g * 4 + r;
            float o = acc[dt][r] * rl[r];
            ob[(tokbase + row) * 512 + h * 64 + dt * 16 + c] = __float2bfloat16(o);
        }
}

// ---------------------------------------------------------------------------
extern "C" void kernel_launch(void* const* d_in, const int* in_sizes, int n_in,
                              void* d_out, int out_size, void* d_ws, size_t ws_size,
                              hipStream_t stream) {
    const float* x   = (const float*)d_in[0];
    const float* Wq  = (const float*)d_in[1];
    const float* Wk  = (const float*)d_in[2];
    const float* Wv  = (const float*)d_in[3];
    const float* Wo  = (const float*)d_in[4];
    const float* bo  = (const float*)d_in[5];
    const float* W1  = (const float*)d_in[6];
    const float* b1  = (const float*)d_in[7];
    const float* W2  = (const float*)d_in[8];
    const float* b2  = (const float*)d_in[9];
    const float* g1  = (const float*)d_in[10];
    const float* be1 = (const float*)d_in[11];
    const float* g2  = (const float*)d_in[12];
    const float* be2 = (const float*)d_in[13];
    float* out = (float*)d_out;

    // Workspace layout (byte offsets, 16B aligned). Peak ~98 MB.
    char* ws = (char*)d_ws;
    __hip_bfloat16* bqT    = (__hip_bfloat16*)(ws);                  // [1536][512]
    __hip_bfloat16* woT    = (__hip_bfloat16*)(ws + 1572864);        // [512][512]
    __hip_bfloat16* w1T    = (__hip_bfloat16*)(ws + 2097152);        // [4096][512]
    __hip_bfloat16* w2T    = (__hip_bfloat16*)(ws + 6291456);        // [512][4096]
    float*          xn     = (float*)(ws + 10485760);                // [8192][512] fp32 (LN1+bo; Wo RMW -> x2)
    __hip_bfloat16* xn_bf  = (__hip_bfloat16*)(ws + 27262976);       // [8192][512] bf16
    __hip_bfloat16* qkv_bf = (__hip_bfloat16*)(ws + 35651584);       // [8192][1536] bf16
    __hip_bfloat16* o_bf   = (__hip_bfloat16*)(ws + 60817408);       // [8192][512] bf16
    __hip_bfloat16* h_bf   = (__hip_bfloat16*)(ws + 35651584);       // [8192][4096] overlay (qkv/o dead by FFN1)

    // 1. startup: LN1 (+bo fold) and all weight repacks, one dispatch
    startup_kernel<<<Mrows + 1280, 256, 0, stream>>>(
        x, g1, be1, bo, xn, xn_bf, Wq, Wk, Wv, Wo, W1, W2, bqT, woT, w1T, w2T);
    // 2. qkv = xn @ Wqkv  -> bf16   (grid 12x64; q columns pre-scaled)
    mfma_gemm<<<768, 256, 0, stream>>>(
        xn_bf, 512, bqT, 512, qkv_bf, 1536, 512, 12);
    // 3. causal attention (MFMA flash, reg-prefetch pipeline) -> o_bf
    attn_mfma<<<Bsz * Hh * (Tt / 128), 512, 0, stream>>>(qkv_bf, o_bf);
    // 4. xn(=x2) += o @ Wo   (128x64 tiles, full K=512, plain RMW, grid 8x64)
    mfma_gemm_n64<<<512, 256, 0, stream>>>(
        o_bf, 512, woT, 512, xn, 512, 512, 8);
    // 5. LN2: out = LN(x2)+b2 (final residual base), xn_bf = LN(x2)
    ln_kernel<<<Mrows, 256, 0, stream>>>(xn, g2, be2, b2, out, xn_bf);
    // 6. h = relu(xn2 @ W1 + b1)  (256x128 tiles, BK=32 single-buf, grid 32x32)
    mfma_gemm256<<<1024, 256, 0, stream>>>(
        xn_bf, 512, w1T, 512, h_bf, HIDs, 512, b1);
    // 7. out += h @ W2  (128x64 tiles, full K=4096, plain RMW, grid 8x64)
    mfma_gemm_n64<<<512, 256, 0, stream>>>(
        h_bf, HIDs, w2T, HIDs, out, 512, HIDs, 8);
}

// Round 13
// 340.001 us; speedup vs baseline: 1.0626x; 1.0626x over previous
//
#include <hip/hip_runtime.h>
#include <hip/hip_bf16.h>
#include <math.h>

// Problem constants (B,T,E)=(4,2048,512), H=8, D=64, HID=H*E=4096.
#define Bsz 4
#define Tt 2048
#define Ee 512
#define Hh 8
#define Dd 64
#define HIDs 4096
#define Mrows (Bsz * Tt)   // 8192 token rows

typedef __attribute__((ext_vector_type(8))) short short8;   // 8 bf16 (4 VGPRs)
typedef __attribute__((ext_vector_type(4))) float f32x4;    // MFMA accumulator

#define AS1 __attribute__((address_space(1)))
#define AS3 __attribute__((address_space(3)))

__device__ __forceinline__ unsigned short f2bfu(float f) {   // RNE float->bf16 bits
    unsigned u = __float_as_uint(f);
    return (unsigned short)((u + 0x7fffu + ((u >> 16) & 1u)) >> 16);
}
__device__ __forceinline__ unsigned short truncbf(float f) { // truncating (P only)
    return (unsigned short)(__float_as_uint(f) >> 16);
}

// ---------------------------------------------------------------------------
// LN body (shared by startup + LN2 kernels).
__device__ __forceinline__ void ln_body(const float* __restrict__ x,
        const float* __restrict__ g, const float* __restrict__ b,
        const float* __restrict__ addb,
        float* __restrict__ out_f, __hip_bfloat16* __restrict__ out_bf,
        int row) {
    int tid = threadIdx.x;
    const float* xr = x + (size_t)row * Ee;
    float v0 = xr[tid];
    float v1 = xr[tid + 256];
    float s = v0 + v1;
    float sq = v0 * v0 + v1 * v1;
#pragma unroll
    for (int off = 32; off > 0; off >>= 1) {
        s  += __shfl_xor(s, off, 64);
        sq += __shfl_xor(sq, off, 64);
    }
    __shared__ float ls[4], lq[4];
    int wid = tid >> 6, lane = tid & 63;
    if (lane == 0) { ls[wid] = s; lq[wid] = sq; }
    __syncthreads();
    s  = ls[0] + ls[1] + ls[2] + ls[3];
    sq = lq[0] + lq[1] + lq[2] + lq[3];
    float mean = s * (1.0f / Ee);
    float var  = sq * (1.0f / Ee) - mean * mean;   // biased var, like jnp.var
    float rstd = rsqrtf(var + 1e-5f);
    float o0 = (v0 - mean) * rstd * g[tid]       + b[tid];
    float o1 = (v1 - mean) * rstd * g[tid + 256] + b[tid + 256];
    float* orow = out_f + (size_t)row * Ee;
    orow[tid]       = o0 + addb[tid];
    orow[tid + 256] = o1 + addb[tid + 256];
    __hip_bfloat16* brow = out_bf + (size_t)row * Ee;
    brow[tid]       = __float2bfloat16(o0);
    brow[tid + 256] = __float2bfloat16(o1);
}

__global__ __launch_bounds__(256) void ln_kernel(const float* __restrict__ x,
        const float* __restrict__ g, const float* __restrict__ b,
        const float* __restrict__ addb,
        float* __restrict__ out_f, __hip_bfloat16* __restrict__ out_bf) {
    ln_body(x, g, b, addb, out_f, out_bf, blockIdx.x);
}

// ---------------------------------------------------------------------------
// Startup: LN1 (blocks [0,8192)) + all weight repacks ([8192,9472)) fused.
__device__ __forceinline__ void tr_tile(const float* __restrict__ in,
        __hip_bfloat16* __restrict__ outp, int R, int C, int c0, int r0) {
    __shared__ float tile[64][65];
    int tc = threadIdx.x & 63, tg = threadIdx.x >> 6;
#pragma unroll
    for (int i = 0; i < 16; ++i) {
        int r = tg * 16 + i;
        tile[r][tc] = in[(size_t)(r0 + r) * C + c0 + tc];
    }
    __syncthreads();
#pragma unroll
    for (int i = 0; i < 16; ++i) {
        int cc = tg * 16 + i;
        outp[(size_t)(c0 + cc) * R + r0 + tc] = __float2bfloat16(tile[tc][cc]);
    }
}
__global__ __launch_bounds__(256) void startup_kernel(
        const float* __restrict__ x, const float* __restrict__ g1,
        const float* __restrict__ be1, const float* __restrict__ bo,
        float* __restrict__ xn, __hip_bfloat16* __restrict__ xn_bf,
        const float* __restrict__ Wq, const float* __restrict__ Wk,
        const float* __restrict__ Wv, const float* __restrict__ Wo,
        const float* __restrict__ W1, const float* __restrict__ W2,
        __hip_bfloat16* __restrict__ bqT, __hip_bfloat16* __restrict__ woT,
        __hip_bfloat16* __restrict__ w1T, __hip_bfloat16* __restrict__ w2T) {
    if (blockIdx.x < Mrows) {
        ln_body(x, g1, be1, bo, xn, xn_bf, blockIdx.x);
        return;
    }
    int blk = blockIdx.x - Mrows;
    if (blk < 192) {                 // qkv: p*64 + h*8 + et
        int p = blk >> 6, h = (blk >> 3) & 7, et = blk & 7;
        const float* W = (p == 0) ? Wq : ((p == 1) ? Wk : Wv);
        float sc = (p == 0) ? 0.022097086912079608f * 1.4426950408889634f : 1.0f;
        __shared__ float tile[64][65];
        int td = threadIdx.x & 63, tg = threadIdx.x >> 6;
#pragma unroll
        for (int i = 0; i < 16; ++i) {
            int e = tg * 16 + i;
            tile[e][td] = W[((size_t)h * Ee + et * 64 + e) * Dd + td] * sc;
        }
        __syncthreads();
#pragma unroll
        for (int i = 0; i < 16; ++i) {
            int d = tg * 16 + i;
            bqT[((size_t)(p * 512 + h * 64 + d)) * Ee + et * 64 + td] =
                __float2bfloat16(tile[td][d]);
        }
    } else if (blk < 256) {
        int t = blk - 192;           // 8x8
        tr_tile(Wo, woT, 512, 512, (t & 7) * 64, (t >> 3) * 64);
    } else if (blk < 768) {
        int t = blk - 256;           // 64x8
        tr_tile(W1, w1T, 512, HIDs, (t & 63) * 64, (t >> 6) * 64);
    } else {
        int t = blk - 768;           // 8x64
        tr_tile(W2, w2T, HIDs, 512, (t & 7) * 64, (t >> 3) * 64);
    }
}

// ---------------------------------------------------------------------------
// bf16 MFMA GEMM (QKV): 128x128 tile, BK=64 two-panel LDS, XCD swizzle.
// Epilogue: per-wave LDS transpose -> uint4 coalesced bf16 stores.
__global__ __launch_bounds__(256) void mfma_gemm(
        const __hip_bfloat16* __restrict__ A, int lda,
        const __hip_bfloat16* __restrict__ B, int ldb,
        __hip_bfloat16* __restrict__ Cb, int ldc, int K, int nx) {
    __shared__ __hip_bfloat16 S[16384];           // As 8192 | Bs 8192 (32 KB)
    __hip_bfloat16* As = S;
    __hip_bfloat16* Bs = S + 8192;
    int tid = threadIdx.x;
    int lane = tid & 63, wave = tid >> 6;
    int wm = wave >> 1, wn = wave & 1;
    int L = blockIdx.x;
    int slots = (int)gridDim.x >> 3;
    int v = (L & 7) * slots + (L >> 3);
    int bx = v % nx, by = v / nx;
    int row0 = by * 128, col0 = bx * 128;
    f32x4 acc[4][4];
#pragma unroll
    for (int i = 0; i < 4; ++i)
#pragma unroll
        for (int j = 0; j < 4; ++j) acc[i][j] = (f32x4){0.f, 0.f, 0.f, 0.f};

    int fr = lane & 15;
    int kq = (lane >> 4) << 3;

    for (int k0 = 0; k0 < K; k0 += 64) {
        __syncthreads();
#pragma unroll
        for (int j = 0; j < 4; ++j) {
            int c  = j * 256 + tid;
            int cb = j * 256 + wave * 64;
            int p  = c >> 9, cp = c & 511;
            int r  = cp >> 2, kg = (cp & 3) << 3;
            int ko = k0 + p * 32 + kg;
            __builtin_amdgcn_global_load_lds(
                (const AS1 void*)(A + (size_t)(row0 + r) * lda + ko),
                (AS3 void*)(As + cb * 8), 16, 0, 0);
            __builtin_amdgcn_global_load_lds(
                (const AS1 void*)(B + (size_t)(col0 + r) * ldb + ko),
                (AS3 void*)(Bs + cb * 8), 16, 0, 0);
        }
        __syncthreads();
#pragma unroll
        for (int ks = 0; ks < 2; ++ks) {
            short8 afr[4], bfr[4];
#pragma unroll
            for (int i = 0; i < 4; ++i) {
                afr[i] = *(const short8*)(As + ks * 4096 + (wm * 64 + i * 16 + fr) * 32 + kq);
                bfr[i] = *(const short8*)(Bs + ks * 4096 + (wn * 64 + i * 16 + fr) * 32 + kq);
            }
#pragma unroll
            for (int i = 0; i < 4; ++i)
#pragma unroll
                for (int j = 0; j < 4; ++j)
                    acc[i][j] = __builtin_amdgcn_mfma_f32_16x16x32_bf16(afr[i], bfr[j], acc[i][j], 0, 0, 0);
        }
    }
    // ---- epilogue: per-wave LDS transpose -> uint4 stores
    __syncthreads();                  // staging LDS reads complete; reuse as Ew
    unsigned short* Ew = (unsigned short*)S + wave * 1152;   // 16 x 72
    const __hip_bfloat16* Er = (const __hip_bfloat16*)Ew;
    int rq = (lane >> 4) << 2;
    int rr = lane >> 2, cb2 = (lane & 3) * 16;
#pragma unroll
    for (int i = 0; i < 4; ++i) {
#pragma unroll
        for (int j = 0; j < 4; ++j)
#pragma unroll
            for (int gi = 0; gi < 4; ++gi)
                Ew[(rq + gi) * 72 + j * 16 + fr] = f2bfu(acc[i][j][gi]);
        uint4 v0 = *(const uint4*)(Er + rr * 72 + cb2);
        uint4 v1 = *(const uint4*)(Er + rr * 72 + cb2 + 8);
        size_t rg = (size_t)(row0 + wm * 64 + i * 16 + rr) * ldc + col0 + wn * 64 + cb2;
        *(uint4*)(Cb + rg)     = v0;
        *(uint4*)(Cb + rg + 8) = v1;
    }
}

// ---------------------------------------------------------------------------
// bf16 MFMA GEMM, 128x64 tile, full K (no split, no atomics). 4 waves x
// (32m x 64n). Epilogue: Cf[ci] += acc (plain RMW; fp32 stores form full
// 64B lines per 16-lane group). Used for Wo (K=512), FFN2 (K=4096).
__global__ __launch_bounds__(256) void mfma_gemm_n64(
        const __hip_bfloat16* __restrict__ A, int lda,
        const __hip_bfloat16* __restrict__ B, int ldb,
        float* __restrict__ Cf, int ldc, int K, int nx) {
    __shared__ __hip_bfloat16 As[2 * 128 * 32];   // 16 KB
    __shared__ __hip_bfloat16 Bs[2 * 64 * 32];    //  8 KB
    int tid = threadIdx.x;
    int lane = tid & 63, wave = tid >> 6;
    int L = blockIdx.x;
    int slots = (int)gridDim.x >> 3;
    int v = (L & 7) * slots + (L >> 3);
    int bx = v % nx, by = v / nx;
    int row0 = by * 128, col0 = bx * 64;
    f32x4 acc[2][4];
#pragma unroll
    for (int i = 0; i < 2; ++i)
#pragma unroll
        for (int j = 0; j < 4; ++j) acc[i][j] = (f32x4){0.f, 0.f, 0.f, 0.f};

    int fr = lane & 15;
    int kq = (lane >> 4) << 3;

    for (int k0 = 0; k0 < K; k0 += 64) {
        __syncthreads();
#pragma unroll
        for (int j = 0; j < 4; ++j) {
            int c  = j * 256 + tid;
            int cb = j * 256 + wave * 64;
            int p  = c >> 9, cp = c & 511;
            int r  = cp >> 2, kg = (cp & 3) << 3;
            __builtin_amdgcn_global_load_lds(
                (const AS1 void*)(A + (size_t)(row0 + r) * lda + k0 + p * 32 + kg),
                (AS3 void*)(As + cb * 8), 16, 0, 0);
        }
#pragma unroll
        for (int j = 0; j < 2; ++j) {
            int c  = j * 256 + tid;
            int cb = j * 256 + wave * 64;
            int p  = c >> 8, cp = c & 255;
            int r  = cp >> 2, kg = (cp & 3) << 3;
            __builtin_amdgcn_global_load_lds(
                (const AS1 void*)(B + (size_t)(col0 + r) * ldb + k0 + p * 32 + kg),
                (AS3 void*)(Bs + cb * 8), 16, 0, 0);
        }
        __syncthreads();
#pragma unroll
        for (int ks = 0; ks < 2; ++ks) {
            short8 afr[2], bfr[4];
#pragma unroll
            for (int i = 0; i < 2; ++i)
                afr[i] = *(const short8*)(As + ks * 4096 + (wave * 32 + i * 16 + fr) * 32 + kq);
#pragma unroll
            for (int j = 0; j < 4; ++j)
                bfr[j] = *(const short8*)(Bs + ks * 2048 + (j * 16 + fr) * 32 + kq);
#pragma unroll
            for (int i = 0; i < 2; ++i)
#pragma unroll
                for (int j = 0; j < 4; ++j)
                    acc[i][j] = __builtin_amdgcn_mfma_f32_16x16x32_bf16(afr[i], bfr[j], acc[i][j], 0, 0, 0);
        }
    }
    int rq = (lane >> 4) << 2;
#pragma unroll
    for (int i = 0; i < 2; ++i)
#pragma unroll
        for (int j = 0; j < 4; ++j)
#pragma unroll
            for (int gidx = 0; gidx < 4; ++gidx) {
                int r = row0 + wave * 32 + i * 16 + rq + gidx;
                int c = col0 + j * 16 + fr;
                Cf[(size_t)r * ldc + c] += acc[i][j][gidx];
            }
}

// ---------------------------------------------------------------------------
// bf16 MFMA GEMM, 256x128 tile (FFN1), BK=64 two-panel PIPELINED (best
// measured config: 82 us). VGPR (140) caps at 3 blocks/CU regardless of LDS
// (measured r12) -- do not shrink LDS hoping for more co-residency.
// Epilogue: per-wave LDS transpose, relu+bias, uint4 stores.
__global__ __launch_bounds__(256) void mfma_gemm256(
        const __hip_bfloat16* __restrict__ A, int lda,
        const __hip_bfloat16* __restrict__ B, int ldb,
        __hip_bfloat16* __restrict__ Cb, int ldc, int K,
        const float* __restrict__ bias) {
    __shared__ __hip_bfloat16 S[24576];           // As 16384 | Bs 8192 (48 KB)
    __hip_bfloat16* As = S;
    __hip_bfloat16* Bs = S + 16384;
    int tid = threadIdx.x;
    int lane = tid & 63, wave = tid >> 6;
    int L = blockIdx.x;
    int k8 = L & 7, sub = L >> 3;     // XCD id (round-robin), slot in XCD
    int sr = k8 >> 1, sc = k8 & 1;    // supertile grid 4x2
    int by = sr * 8 + (sub >> 4);
    int bx = sc * 16 + (sub & 15);
    int row0 = by * 256, col0 = bx * 128;
    f32x4 acc[4][8];
#pragma unroll
    for (int i = 0; i < 4; ++i)
#pragma unroll
        for (int j = 0; j < 8; ++j) acc[i][j] = (f32x4){0.f, 0.f, 0.f, 0.f};

    int fr = lane & 15;
    int kq = (lane >> 4) << 3;
    int nsteps = K >> 5;              // 32-wide k steps

#define STAGE256(st, buf)                                                     \
    do {                                                                      \
        int ko_ = (st) << 5;                                                  \
        _Pragma("unroll")                                                     \
        for (int j = 0; j < 4; ++j) {                                         \
            int c = j * 256 + tid;                                            \
            int cb = j * 256 + wave * 64;                                     \
            int r = c >> 2, kg = (c & 3) << 3;                                \
            __builtin_amdgcn_global_load_lds(                                 \
                (const AS1 void*)(A + (size_t)(row0 + r) * lda + ko_ + kg),   \
                (AS3 void*)(As + (buf) * 8192 + cb * 8), 16, 0, 0);           \
        }                                                                     \
        _Pragma("unroll")                                                     \
        for (int j = 0; j < 2; ++j) {                                         \
            int c = j * 256 + tid;                                            \
            int cb = j * 256 + wave * 64;                                     \
            int r = c >> 2, kg = (c & 3) << 3;                                \
            __builtin_amdgcn_global_load_lds(                                 \
                (const AS1 void*)(B + (size_t)(col0 + r) * ldb + ko_ + kg),   \
                (AS3 void*)(Bs + (buf) * 4096 + cb * 8), 16, 0, 0);           \
        }                                                                     \
    } while (0)

    STAGE256(0, 0);
    __syncthreads();
    for (int st = 0; st < nsteps; ++st) {
        int buf = st & 1;
        if (st + 1 < nsteps) STAGE256(st + 1, buf ^ 1);
        short8 afr[4], bfr[8];
#pragma unroll
        for (int i = 0; i < 4; ++i)
            afr[i] = *(const short8*)(As + buf * 8192 + (wave * 64 + i * 16 + fr) * 32 + kq);
#pragma unroll
        for (int j = 0; j < 8; ++j)
            bfr[j] = *(const short8*)(Bs + buf * 4096 + (j * 16 + fr) * 32 + kq);
#pragma unroll
        for (int i = 0; i < 4; ++i)
#pragma unroll
            for (int j = 0; j < 8; ++j)
                acc[i][j] = __builtin_amdgcn_mfma_f32_16x16x32_bf16(afr[i], bfr[j], acc[i][j], 0, 0, 0);
        __syncthreads();
    }
#undef STAGE256

    // ---- epilogue: bias+relu -> per-wave LDS transpose -> uint4 stores
    float bv[8];
#pragma unroll
    for (int j = 0; j < 8; ++j) bv[j] = bias[col0 + j * 16 + fr];
    unsigned short* Ew = (unsigned short*)S + wave * 2176;   // 16 x 136
    const __hip_bfloat16* Er = (const __hip_bfloat16*)Ew;
    int rq = (lane >> 4) << 2;
    int rr = lane >> 2, cb2 = (lane & 3) * 32;
#pragma unroll
    for (int i = 0; i < 4; ++i) {
#pragma unroll
        for (int j = 0; j < 8; ++j)
#pragma unroll
            for (int gi = 0; gi < 4; ++gi) {
                float t = acc[i][j][gi] + bv[j];
                Ew[(rq + gi) * 136 + j * 16 + fr] = f2bfu(t > 0.f ? t : 0.f);
            }
        size_t rg = (size_t)(row0 + wave * 64 + i * 16 + rr) * ldc + col0 + cb2;
#pragma unroll
        for (int u = 0; u < 4; ++u)
            *(uint4*)(Cb + rg + u * 8) = *(const uint4*)(Er + rr * 136 + cb2 + u * 8);
    }
}

// ---------------------------------------------------------------------------
// MFMA flash attention, no-max softmax, reg-prefetch + K/V LDS ping-pong:
// ONE barrier per tile (write buf(t) -> barrier -> prefetch(t+1) -> compute
// buf(t); a wave's buf reads finish before it enters the next barrier, and
// iteration t+1 writes the other buffer). One block = 128 Q rows of one
// (b,h); 8 waves x 16 rows. Q pre-scaled (T^-0.5*log2e folded into Wq).
__global__ __launch_bounds__(512) void attn_mfma(const __hip_bfloat16* __restrict__ qkvb,
        __hip_bfloat16* __restrict__ ob) {
    __shared__ __hip_bfloat16 KsS[2][64 * 72];  // K tiles [s][d], ping-pong
    __shared__ __hip_bfloat16 VtS[2][64 * 72];  // V^T tiles [d][s], ping-pong
    __shared__ __hip_bfloat16 PsS[8 * 16 * 72]; // P [wave][q][s] bf16; Q overlays
    __hip_bfloat16* Qs = PsS;                   // Q staging [128 q][72]

    const unsigned short* q16 = (const unsigned short*)qkvb;
    int tid  = threadIdx.x;
    int lane = tid & 63, wave = tid >> 6;
    int g = lane >> 4, c = lane & 15;
    int blk = blockIdx.x;
    int qb  = 15 - (blk >> 5);                // global heavy-first
    int bh  = blk & 31;
    int b = bh >> 3, h = bh & 7;
    int base = qb * 128;
    size_t tokbase = (size_t)b * Tt;
    int qoff = h * 64, koff = 512 + h * 64, voff = 1024 + h * 64;

    {   // stage Q (already scaled) into Qs[q][72], 128 rows
        int q = tid >> 2, dg = (tid & 3) * 16;
        const unsigned short* src = q16 + (tokbase + base + q) * 1536 + qoff + dg;
        uint4 a  = *(const uint4*)src;
        uint4 b4 = *(const uint4*)(src + 8);
        *(uint4*)(Qs + q * 72 + dg)     = a;
        *(uint4*)(Qs + q * 72 + dg + 8) = b4;
    }
    __syncthreads();
    short8 aq[2];
    aq[0] = *(const short8*)(Qs + (wave * 16 + c) * 72 + g * 8);
    aq[1] = *(const short8*)(Qs + (wave * 16 + c) * 72 + 32 + g * 8);

    short8 ones;
#pragma unroll
    for (int i = 0; i < 8; ++i) ones[i] = (short)0x3F80;   // bf16 1.0

    f32x4 acc[4];
#pragma unroll
    for (int dt = 0; dt < 4; ++dt) acc[dt] = (f32x4){0.f, 0.f, 0.f, 0.f};
    f32x4 accL = (f32x4){0.f, 0.f, 0.f, 0.f};   // row-sums of P
    __hip_bfloat16* Psw = PsS + wave * (16 * 72);
    unsigned short* Psw16 = (unsigned short*)Psw;

    // prefetch lane roles
    int s_k = tid >> 3, dg_k = (tid & 7) * 8;       // K: 1 uint4 per thread
    int sp = (tid & 31) * 2, dg4 = (tid >> 5) * 4;  // V: 2 uint2 per thread
    uint4 kreg; uint2 va, vb;
    {   // prologue: load tile 0
        kreg = *(const uint4*)(q16 + (tokbase + s_k) * 1536 + koff + dg_k);
        const unsigned short* r0p = q16 + (tokbase + sp) * 1536 + voff + dg4;
        va = *(const uint2*)r0p;
        vb = *(const uint2*)(r0p + 1536);
    }

    int tmax = 2 * qb + 1;
    for (int tile = 0; tile <= tmax; ++tile) {
        int buf = tile & 1;
        // ---- write prefetched K/V into this tile's buffer
        *(uint4*)(KsS[buf] + s_k * 72 + dg_k) = kreg;
        {
            unsigned a0[2] = {va.x, va.y};
            unsigned b0[2] = {vb.x, vb.y};
#pragma unroll
            for (int i = 0; i < 2; ++i) {
                unsigned p0 = (a0[i] & 0xffffu) | (b0[i] << 16);
                unsigned p1 = (a0[i] >> 16) | (b0[i] & 0xffff0000u);
                *(unsigned*)(VtS[buf] + (dg4 + 2 * i) * 72 + sp)     = p0;
                *(unsigned*)(VtS[buf] + (dg4 + 2 * i + 1) * 72 + sp) = p1;
            }
        }
        __syncthreads();                      // single barrier per tile
        if (tile < tmax) {                    // prefetch tile+1 under compute
            int s1 = (tile + 1) * 64;
            kreg = *(const uint4*)(q16 + (tokbase + s1 + s_k) * 1536 + koff + dg_k);
            const unsigned short* r0p = q16 + (tokbase + s1 + sp) * 1536 + voff + dg4;
            va = *(const uint2*)r0p;
            vb = *(const uint2*)(r0p + 1536);
        }
        if (tile == tmax && wave < 4) continue;   // fully masked for waves 0-3
        f32x4 Sc[4];
#pragma unroll
        for (int st = 0; st < 4; ++st) Sc[st] = (f32x4){0.f, 0.f, 0.f, 0.f};
#pragma unroll
        for (int ks = 0; ks < 2; ++ks)
#pragma unroll
            for (int st = 0; st < 4; ++st) {
                short8 bk = *(const short8*)(KsS[buf] + (st * 16 + c) * 72 + ks * 32 + g * 8);
                Sc[st] = __builtin_amdgcn_mfma_f32_16x16x32_bf16(aq[ks], bk, Sc[st], 0, 0, 0);
            }
        if (tile >= 2 * qb) {                 // diagonal-straddling tiles
            int s0 = tile * 64;
            int qg = base + wave * 16 + g * 4;
#pragma unroll
            for (int st = 0; st < 4; ++st) {
                int sg = s0 + st * 16 + c;
#pragma unroll
                for (int r = 0; r < 4; ++r)
                    if (sg > qg + r) Sc[st][r] = -1e30f;
            }
        }
#pragma unroll
        for (int st = 0; st < 4; ++st)
#pragma unroll
            for (int r = 0; r < 4; ++r)
                Psw16[(g * 4 + r) * 72 + st * 16 + c] =
                    truncbf(__builtin_amdgcn_exp2f(Sc[st][r]));
#pragma unroll
        for (int ks = 0; ks < 2; ++ks) {
            short8 ap = *(const short8*)(Psw + c * 72 + ks * 32 + g * 8);
            accL = __builtin_amdgcn_mfma_f32_16x16x32_bf16(ap, ones, accL, 0, 0, 0);
#pragma unroll
            for (int dt = 0; dt < 4; ++dt) {
                short8 bv = *(const short8*)(VtS[buf] + (dt * 16 + c) * 72 + ks * 32 + g * 8);
                acc[dt] = __builtin_amdgcn_mfma_f32_16x16x32_bf16(ap, bv, acc[dt], 0, 0, 0);
            }
        }
    }
    float rl[4];
#pragma unroll
    for (int r = 0; r < 4; ++r) rl[r] = 1.0f / accL[r];
#pragma unroll
    for (int dt = 0; dt < 4; ++dt)
#pragma unroll
        for (int r = 0; r < 4; ++r) {
            int row = base + wave * 16 + g * 4 + r;
            float o = acc[dt][r] * rl[r];
            ob[(tokbase + row) * 512 + h * 64 + dt * 16 + c] = __float2bfloat16(o);
        }
}

// ---------------------------------------------------------------------------
extern "C" void kernel_launch(void* const* d_in, const int* in_sizes, int n_in,
                              void* d_out, int out_size, void* d_ws, size_t ws_size,
                              hipStream_t stream) {
    const float* x   = (const float*)d_in[0];
    const float* Wq  = (const float*)d_in[1];
    const float* Wk  = (const float*)d_in[2];
    const float* Wv  = (const float*)d_in[3];
    const float* Wo  = (const float*)d_in[4];
    const float* bo  = (const float*)d_in[5];
    const float* W1  = (const float*)d_in[6];
    const float* b1  = (const float*)d_in[7];
    const float* W2  = (const float*)d_in[8];
    const float* b2  = (const float*)d_in[9];
    const float* g1  = (const float*)d_in[10];
    const float* be1 = (const float*)d_in[11];
    const float* g2  = (const float*)d_in[12];
    const float* be2 = (const float*)d_in[13];
    float* out = (float*)d_out;

    // Workspace layout (byte offsets, 16B aligned). Peak ~98 MB.
    char* ws = (char*)d_ws;
    __hip_bfloat16* bqT    = (__hip_bfloat16*)(ws);                  // [1536][512]
    __hip_bfloat16* woT    = (__hip_bfloat16*)(ws + 1572864);        // [512][512]
    __hip_bfloat16* w1T    = (__hip_bfloat16*)(ws + 2097152);        // [4096][512]
    __hip_bfloat16* w2T    = (__hip_bfloat16*)(ws + 6291456);        // [512][4096]
    float*          xn     = (float*)(ws + 10485760);                // [8192][512] fp32 (LN1+bo; Wo RMW -> x2)
    __hip_bfloat16* xn_bf  = (__hip_bfloat16*)(ws + 27262976);       // [8192][512] bf16
    __hip_bfloat16* qkv_bf = (__hip_bfloat16*)(ws + 35651584);       // [8192][1536] bf16
    __hip_bfloat16* o_bf   = (__hip_bfloat16*)(ws + 60817408);       // [8192][512] bf16
    __hip_bfloat16* h_bf   = (__hip_bfloat16*)(ws + 35651584);       // [8192][4096] overlay (qkv/o dead by FFN1)

    // 1. startup: LN1 (+bo fold) and all weight repacks, one dispatch
    startup_kernel<<<Mrows + 1280, 256, 0, stream>>>(
        x, g1, be1, bo, xn, xn_bf, Wq, Wk, Wv, Wo, W1, W2, bqT, woT, w1T, w2T);
    // 2. qkv = xn @ Wqkv  -> bf16   (grid 12x64; q columns pre-scaled)
    mfma_gemm<<<768, 256, 0, stream>>>(
        xn_bf, 512, bqT, 512, qkv_bf, 1536, 512, 12);
    // 3. causal attention (MFMA flash, 1 barrier/tile) -> o_bf
    attn_mfma<<<Bsz * Hh * (Tt / 128), 512, 0, stream>>>(qkv_bf, o_bf);
    // 4. xn(=x2) += o @ Wo   (128x64 tiles, full K=512, plain RMW, grid 8x64)
    mfma_gemm_n64<<<512, 256, 0, stream>>>(
        o_bf, 512, woT, 512, xn, 512, 512, 8);
    // 5. LN2: out = LN(x2)+b2 (final residual base), xn_bf = LN(x2)
    ln_kernel<<<Mrows, 256, 0, stream>>>(xn, g2, be2, b2, out, xn_bf);
    // 6. h = relu(xn2 @ W1 + b1)  (256x128 tiles, BK=64 pipelined, grid 32x32)
    mfma_gemm256<<<1024, 256, 0, stream>>>(
        xn_bf, 512, w1T, 512, h_bf, HIDs, 512, b1);
    // 7. out += h @ W2  (128x64 tiles, full K=4096, plain RMW, grid 8x64)
    mfma_gemm_n64<<<512, 256, 0, stream>>>(
        h_bf, HIDs, w2T, HIDs, out, 512, HIDs, 8);
}

// Round 14
// 338.792 us; speedup vs baseline: 1.0664x; 1.0036x over previous
//
#include <hip/hip_runtime.h>
#include <hip/hip_bf16.h>
#include <math.h>

// Problem constants (B,T,E)=(4,2048,512), H=8, D=64, HID=H*E=4096.
#define Bsz 4
#define Tt 2048
#define Ee 512
#define Hh 8
#define Dd 64
#define HIDs 4096
#define Mrows (Bsz * Tt)   // 8192 token rows

typedef __attribute__((ext_vector_type(8))) short short8;    // 8 bf16 (4 VGPRs)
typedef __attribute__((ext_vector_type(4))) float f32x4;     // 16x16 MFMA acc
typedef __attribute__((ext_vector_type(16))) float f32x16;   // 32x32 MFMA acc

#define AS1 __attribute__((address_space(1)))
#define AS3 __attribute__((address_space(3)))

__device__ __forceinline__ unsigned short f2bfu(float f) {   // RNE float->bf16 bits
    unsigned u = __float_as_uint(f);
    return (unsigned short)((u + 0x7fffu + ((u >> 16) & 1u)) >> 16);
}
__device__ __forceinline__ unsigned short truncbf(float f) { // truncating (P only)
    return (unsigned short)(__float_as_uint(f) >> 16);
}

// ---------------------------------------------------------------------------
// LN body (shared by startup + LN2 kernels).
__device__ __forceinline__ void ln_body(const float* __restrict__ x,
        const float* __restrict__ g, const float* __restrict__ b,
        const float* __restrict__ addb,
        float* __restrict__ out_f, __hip_bfloat16* __restrict__ out_bf,
        int row) {
    int tid = threadIdx.x;
    const float* xr = x + (size_t)row * Ee;
    float v0 = xr[tid];
    float v1 = xr[tid + 256];
    float s = v0 + v1;
    float sq = v0 * v0 + v1 * v1;
#pragma unroll
    for (int off = 32; off > 0; off >>= 1) {
        s  += __shfl_xor(s, off, 64);
        sq += __shfl_xor(sq, off, 64);
    }
    __shared__ float ls[4], lq[4];
    int wid = tid >> 6, lane = tid & 63;
    if (lane == 0) { ls[wid] = s; lq[wid] = sq; }
    __syncthreads();
    s  = ls[0] + ls[1] + ls[2] + ls[3];
    sq = lq[0] + lq[1] + lq[2] + lq[3];
    float mean = s * (1.0f / Ee);
    float var  = sq * (1.0f / Ee) - mean * mean;   // biased var, like jnp.var
    float rstd = rsqrtf(var + 1e-5f);
    float o0 = (v0 - mean) * rstd * g[tid]       + b[tid];
    float o1 = (v1 - mean) * rstd * g[tid + 256] + b[tid + 256];
    float* orow = out_f + (size_t)row * Ee;
    orow[tid]       = o0 + addb[tid];
    orow[tid + 256] = o1 + addb[tid + 256];
    __hip_bfloat16* brow = out_bf + (size_t)row * Ee;
    brow[tid]       = __float2bfloat16(o0);
    brow[tid + 256] = __float2bfloat16(o1);
}

__global__ __launch_bounds__(256) void ln_kernel(const float* __restrict__ x,
        const float* __restrict__ g, const float* __restrict__ b,
        const float* __restrict__ addb,
        float* __restrict__ out_f, __hip_bfloat16* __restrict__ out_bf) {
    ln_body(x, g, b, addb, out_f, out_bf, blockIdx.x);
}

// ---------------------------------------------------------------------------
// Startup: LN1 (blocks [0,8192)) + all weight repacks ([8192,9472)) fused.
__device__ __forceinline__ void tr_tile(const float* __restrict__ in,
        __hip_bfloat16* __restrict__ outp, int R, int C, int c0, int r0) {
    __shared__ float tile[64][65];
    int tc = threadIdx.x & 63, tg = threadIdx.x >> 6;
#pragma unroll
    for (int i = 0; i < 16; ++i) {
        int r = tg * 16 + i;
        tile[r][tc] = in[(size_t)(r0 + r) * C + c0 + tc];
    }
    __syncthreads();
#pragma unroll
    for (int i = 0; i < 16; ++i) {
        int cc = tg * 16 + i;
        outp[(size_t)(c0 + cc) * R + r0 + tc] = __float2bfloat16(tile[tc][cc]);
    }
}
__global__ __launch_bounds__(256) void startup_kernel(
        const float* __restrict__ x, const float* __restrict__ g1,
        const float* __restrict__ be1, const float* __restrict__ bo,
        float* __restrict__ xn, __hip_bfloat16* __restrict__ xn_bf,
        const float* __restrict__ Wq, const float* __restrict__ Wk,
        const float* __restrict__ Wv, const float* __restrict__ Wo,
        const float* __restrict__ W1, const float* __restrict__ W2,
        __hip_bfloat16* __restrict__ bqT, __hip_bfloat16* __restrict__ woT,
        __hip_bfloat16* __restrict__ w1T, __hip_bfloat16* __restrict__ w2T) {
    if (blockIdx.x < Mrows) {
        ln_body(x, g1, be1, bo, xn, xn_bf, blockIdx.x);
        return;
    }
    int blk = blockIdx.x - Mrows;
    if (blk < 192) {                 // qkv: p*64 + h*8 + et
        int p = blk >> 6, h = (blk >> 3) & 7, et = blk & 7;
        const float* W = (p == 0) ? Wq : ((p == 1) ? Wk : Wv);
        float sc = (p == 0) ? 0.022097086912079608f * 1.4426950408889634f : 1.0f;
        __shared__ float tile[64][65];
        int td = threadIdx.x & 63, tg = threadIdx.x >> 6;
#pragma unroll
        for (int i = 0; i < 16; ++i) {
            int e = tg * 16 + i;
            tile[e][td] = W[((size_t)h * Ee + et * 64 + e) * Dd + td] * sc;
        }
        __syncthreads();
#pragma unroll
        for (int i = 0; i < 16; ++i) {
            int d = tg * 16 + i;
            bqT[((size_t)(p * 512 + h * 64 + d)) * Ee + et * 64 + td] =
                __float2bfloat16(tile[td][d]);
        }
    } else if (blk < 256) {
        int t = blk - 192;           // 8x8
        tr_tile(Wo, woT, 512, 512, (t & 7) * 64, (t >> 3) * 64);
    } else if (blk < 768) {
        int t = blk - 256;           // 64x8
        tr_tile(W1, w1T, 512, HIDs, (t & 63) * 64, (t >> 6) * 64);
    } else {
        int t = blk - 768;           // 8x64
        tr_tile(W2, w2T, HIDs, 512, (t & 7) * 64, (t >> 3) * 64);
    }
}

// ---------------------------------------------------------------------------
// bf16 MFMA GEMM (QKV): 128x128 tile, BK=64 two-panel LDS, XCD swizzle.
// Epilogue: per-wave LDS transpose -> uint4 coalesced bf16 stores.
__global__ __launch_bounds__(256) void mfma_gemm(
        const __hip_bfloat16* __restrict__ A, int lda,
        const __hip_bfloat16* __restrict__ B, int ldb,
        __hip_bfloat16* __restrict__ Cb, int ldc, int K, int nx) {
    __shared__ __hip_bfloat16 S[16384];           // As 8192 | Bs 8192 (32 KB)
    __hip_bfloat16* As = S;
    __hip_bfloat16* Bs = S + 8192;
    int tid = threadIdx.x;
    int lane = tid & 63, wave = tid >> 6;
    int wm = wave >> 1, wn = wave & 1;
    int L = blockIdx.x;
    int slots = (int)gridDim.x >> 3;
    int v = (L & 7) * slots + (L >> 3);
    int bx = v % nx, by = v / nx;
    int row0 = by * 128, col0 = bx * 128;
    f32x4 acc[4][4];
#pragma unroll
    for (int i = 0; i < 4; ++i)
#pragma unroll
        for (int j = 0; j < 4; ++j) acc[i][j] = (f32x4){0.f, 0.f, 0.f, 0.f};

    int fr = lane & 15;
    int kq = (lane >> 4) << 3;

    for (int k0 = 0; k0 < K; k0 += 64) {
        __syncthreads();
#pragma unroll
        for (int j = 0; j < 4; ++j) {
            int c  = j * 256 + tid;
            int cb = j * 256 + wave * 64;
            int p  = c >> 9, cp = c & 511;
            int r  = cp >> 2, kg = (cp & 3) << 3;
            int ko = k0 + p * 32 + kg;
            __builtin_amdgcn_global_load_lds(
                (const AS1 void*)(A + (size_t)(row0 + r) * lda + ko),
                (AS3 void*)(As + cb * 8), 16, 0, 0);
            __builtin_amdgcn_global_load_lds(
                (const AS1 void*)(B + (size_t)(col0 + r) * ldb + ko),
                (AS3 void*)(Bs + cb * 8), 16, 0, 0);
        }
        __syncthreads();
#pragma unroll
        for (int ks = 0; ks < 2; ++ks) {
            short8 afr[4], bfr[4];
#pragma unroll
            for (int i = 0; i < 4; ++i) {
                afr[i] = *(const short8*)(As + ks * 4096 + (wm * 64 + i * 16 + fr) * 32 + kq);
                bfr[i] = *(const short8*)(Bs + ks * 4096 + (wn * 64 + i * 16 + fr) * 32 + kq);
            }
#pragma unroll
            for (int i = 0; i < 4; ++i)
#pragma unroll
                for (int j = 0; j < 4; ++j)
                    acc[i][j] = __builtin_amdgcn_mfma_f32_16x16x32_bf16(afr[i], bfr[j], acc[i][j], 0, 0, 0);
        }
    }
    // ---- epilogue: per-wave LDS transpose -> uint4 stores
    __syncthreads();                  // staging LDS reads complete; reuse as Ew
    unsigned short* Ew = (unsigned short*)S + wave * 1152;   // 16 x 72
    const __hip_bfloat16* Er = (const __hip_bfloat16*)Ew;
    int rq = (lane >> 4) << 2;
    int rr = lane >> 2, cb2 = (lane & 3) * 16;
#pragma unroll
    for (int i = 0; i < 4; ++i) {
#pragma unroll
        for (int j = 0; j < 4; ++j)
#pragma unroll
            for (int gi = 0; gi < 4; ++gi)
                Ew[(rq + gi) * 72 + j * 16 + fr] = f2bfu(acc[i][j][gi]);
        uint4 v0 = *(const uint4*)(Er + rr * 72 + cb2);
        uint4 v1 = *(const uint4*)(Er + rr * 72 + cb2 + 8);
        size_t rg = (size_t)(row0 + wm * 64 + i * 16 + rr) * ldc + col0 + wn * 64 + cb2;
        *(uint4*)(Cb + rg)     = v0;
        *(uint4*)(Cb + rg + 8) = v1;
    }
}

// ---------------------------------------------------------------------------
// bf16 MFMA GEMM, 128x64 tile, full K (no split, no atomics). 4 waves x
// (32m x 64n). Epilogue: Cf[ci] += acc (plain RMW). Wo (K=512), FFN2 (K=4096).
__global__ __launch_bounds__(256) void mfma_gemm_n64(
        const __hip_bfloat16* __restrict__ A, int lda,
        const __hip_bfloat16* __restrict__ B, int ldb,
        float* __restrict__ Cf, int ldc, int K, int nx) {
    __shared__ __hip_bfloat16 As[2 * 128 * 32];   // 16 KB
    __shared__ __hip_bfloat16 Bs[2 * 64 * 32];    //  8 KB
    int tid = threadIdx.x;
    int lane = tid & 63, wave = tid >> 6;
    int L = blockIdx.x;
    int slots = (int)gridDim.x >> 3;
    int v = (L & 7) * slots + (L >> 3);
    int bx = v % nx, by = v / nx;
    int row0 = by * 128, col0 = bx * 64;
    f32x4 acc[2][4];
#pragma unroll
    for (int i = 0; i < 2; ++i)
#pragma unroll
        for (int j = 0; j < 4; ++j) acc[i][j] = (f32x4){0.f, 0.f, 0.f, 0.f};

    int fr = lane & 15;
    int kq = (lane >> 4) << 3;

    for (int k0 = 0; k0 < K; k0 += 64) {
        __syncthreads();
#pragma unroll
        for (int j = 0; j < 4; ++j) {
            int c  = j * 256 + tid;
            int cb = j * 256 + wave * 64;
            int p  = c >> 9, cp = c & 511;
            int r  = cp >> 2, kg = (cp & 3) << 3;
            __builtin_amdgcn_global_load_lds(
                (const AS1 void*)(A + (size_t)(row0 + r) * lda + k0 + p * 32 + kg),
                (AS3 void*)(As + cb * 8), 16, 0, 0);
        }
#pragma unroll
        for (int j = 0; j < 2; ++j) {
            int c  = j * 256 + tid;
            int cb = j * 256 + wave * 64;
            int p  = c >> 8, cp = c & 255;
            int r  = cp >> 2, kg = (cp & 3) << 3;
            __builtin_amdgcn_global_load_lds(
                (const AS1 void*)(B + (size_t)(col0 + r) * ldb + k0 + p * 32 + kg),
                (AS3 void*)(Bs + cb * 8), 16, 0, 0);
        }
        __syncthreads();
#pragma unroll
        for (int ks = 0; ks < 2; ++ks) {
            short8 afr[2], bfr[4];
#pragma unroll
            for (int i = 0; i < 2; ++i)
                afr[i] = *(const short8*)(As + ks * 4096 + (wave * 32 + i * 16 + fr) * 32 + kq);
#pragma unroll
            for (int j = 0; j < 4; ++j)
                bfr[j] = *(const short8*)(Bs + ks * 2048 + (j * 16 + fr) * 32 + kq);
#pragma unroll
            for (int i = 0; i < 2; ++i)
#pragma unroll
                for (int j = 0; j < 4; ++j)
                    acc[i][j] = __builtin_amdgcn_mfma_f32_16x16x32_bf16(afr[i], bfr[j], acc[i][j], 0, 0, 0);
        }
    }
    int rq = (lane >> 4) << 2;
#pragma unroll
    for (int i = 0; i < 2; ++i)
#pragma unroll
        for (int j = 0; j < 4; ++j)
#pragma unroll
            for (int gidx = 0; gidx < 4; ++gidx) {
                int r = row0 + wave * 32 + i * 16 + rq + gidx;
                int c = col0 + j * 16 + fr;
                Cf[(size_t)r * ldc + c] += acc[i][j][gidx];
            }
}

// ---------------------------------------------------------------------------
// bf16 MFMA GEMM, 256x128 tile (FFN1), BK=64 two-panel PIPELINED (best
// measured config: 80 us). VGPR caps at 3 blocks/CU regardless of LDS (r12).
// Epilogue: per-wave LDS transpose, relu+bias, uint4 stores.
__global__ __launch_bounds__(256) void mfma_gemm256(
        const __hip_bfloat16* __restrict__ A, int lda,
        const __hip_bfloat16* __restrict__ B, int ldb,
        __hip_bfloat16* __restrict__ Cb, int ldc, int K,
        const float* __restrict__ bias) {
    __shared__ __hip_bfloat16 S[24576];           // As 16384 | Bs 8192 (48 KB)
    __hip_bfloat16* As = S;
    __hip_bfloat16* Bs = S + 16384;
    int tid = threadIdx.x;
    int lane = tid & 63, wave = tid >> 6;
    int L = blockIdx.x;
    int k8 = L & 7, sub = L >> 3;     // XCD id (round-robin), slot in XCD
    int sr = k8 >> 1, sc = k8 & 1;    // supertile grid 4x2
    int by = sr * 8 + (sub >> 4);
    int bx = sc * 16 + (sub & 15);
    int row0 = by * 256, col0 = bx * 128;
    f32x4 acc[4][8];
#pragma unroll
    for (int i = 0; i < 4; ++i)
#pragma unroll
        for (int j = 0; j < 8; ++j) acc[i][j] = (f32x4){0.f, 0.f, 0.f, 0.f};

    int fr = lane & 15;
    int kq = (lane >> 4) << 3;
    int nsteps = K >> 5;              // 32-wide k steps

#define STAGE256(st, buf)                                                     \
    do {                                                                      \
        int ko_ = (st) << 5;                                                  \
        _Pragma("unroll")                                                     \
        for (int j = 0; j < 4; ++j) {                                         \
            int c = j * 256 + tid;                                            \
            int cb = j * 256 + wave * 64;                                     \
            int r = c >> 2, kg = (c & 3) << 3;                                \
            __builtin_amdgcn_global_load_lds(                                 \
                (const AS1 void*)(A + (size_t)(row0 + r) * lda + ko_ + kg),   \
                (AS3 void*)(As + (buf) * 8192 + cb * 8), 16, 0, 0);           \
        }                                                                     \
        _Pragma("unroll")                                                     \
        for (int j = 0; j < 2; ++j) {                                         \
            int c = j * 256 + tid;                                            \
            int cb = j * 256 + wave * 64;                                     \
            int r = c >> 2, kg = (c & 3) << 3;                                \
            __builtin_amdgcn_global_load_lds(                                 \
                (const AS1 void*)(B + (size_t)(col0 + r) * ldb + ko_ + kg),   \
                (AS3 void*)(Bs + (buf) * 4096 + cb * 8), 16, 0, 0);           \
        }                                                                     \
    } while (0)

    STAGE256(0, 0);
    __syncthreads();
    for (int st = 0; st < nsteps; ++st) {
        int buf = st & 1;
        if (st + 1 < nsteps) STAGE256(st + 1, buf ^ 1);
        short8 afr[4], bfr[8];
#pragma unroll
        for (int i = 0; i < 4; ++i)
            afr[i] = *(const short8*)(As + buf * 8192 + (wave * 64 + i * 16 + fr) * 32 + kq);
#pragma unroll
        for (int j = 0; j < 8; ++j)
            bfr[j] = *(const short8*)(Bs + buf * 4096 + (j * 16 + fr) * 32 + kq);
#pragma unroll
        for (int i = 0; i < 4; ++i)
#pragma unroll
            for (int j = 0; j < 8; ++j)
                acc[i][j] = __builtin_amdgcn_mfma_f32_16x16x32_bf16(afr[i], bfr[j], acc[i][j], 0, 0, 0);
        __syncthreads();
    }
#undef STAGE256

    // ---- epilogue: bias+relu -> per-wave LDS transpose -> uint4 stores
    float bv[8];
#pragma unroll
    for (int j = 0; j < 8; ++j) bv[j] = bias[col0 + j * 16 + fr];
    unsigned short* Ew = (unsigned short*)S + wave * 2176;   // 16 x 136
    const __hip_bfloat16* Er = (const __hip_bfloat16*)Ew;
    int rq = (lane >> 4) << 2;
    int rr = lane >> 2, cb2 = (lane & 3) * 32;
#pragma unroll
    for (int i = 0; i < 4; ++i) {
#pragma unroll
        for (int j = 0; j < 8; ++j)
#pragma unroll
            for (int gi = 0; gi < 4; ++gi) {
                float t = acc[i][j][gi] + bv[j];
                Ew[(rq + gi) * 136 + j * 16 + fr] = f2bfu(t > 0.f ? t : 0.f);
            }
        size_t rg = (size_t)(row0 + wave * 64 + i * 16 + rr) * ldc + col0 + cb2;
#pragma unroll
        for (int u = 0; u < 4; ++u)
            *(uint4*)(Cb + rg + u * 8) = *(const uint4*)(Er + rr * 136 + cb2 + u * 8);
    }
}

// ---------------------------------------------------------------------------
// MFMA flash attention, 32x32x16 MFMAs (2x FLOP per LDS operand read vs
// 16x16x32 -- the kernel is LDS-throughput-bound). One block = 128 Q rows of
// one (b,h); 4 waves x 32 rows, 256 threads. Single barrier per tile with
// K/V LDS ping-pong + register prefetch (r13 structure). No-max softmax
// (exp2; T^-0.5*log2e pre-folded into Wq); row-sums via B=ones MFMA.
// Layouts (m74/m101-verified C/D): col=lane&31, row=(reg&3)+8*(reg>>2)+
// 4*(lane>>5); A/B frag: m|n=lane&31, k=(lane>>5)*8+j.
__global__ __launch_bounds__(256) void attn_mfma(const __hip_bfloat16* __restrict__ qkvb,
        __hip_bfloat16* __restrict__ ob) {
    __shared__ __hip_bfloat16 KsS[2][64 * 72];  // K tiles [s][d], ping-pong
    __shared__ __hip_bfloat16 VtS[2][64 * 72];  // V^T tiles [d][s], ping-pong
    __shared__ __hip_bfloat16 PsS[4 * 32 * 72]; // P [wave][32 q][s]; Q overlays
    __hip_bfloat16* Qs = PsS;                   // Q staging [128 q][72]

    const unsigned short* q16 = (const unsigned short*)qkvb;
    int tid  = threadIdx.x;
    int lane = tid & 63, wave = tid >> 6;
    int l31 = lane & 31, l5 = lane >> 5;
    int blk = blockIdx.x;
    int qb  = 15 - (blk >> 5);                // global heavy-first
    int bh  = blk & 31;
    int b = bh >> 3, h = bh & 7;
    int base = qb * 128;
    size_t tokbase = (size_t)b * Tt;
    int qoff = h * 64, koff = 512 + h * 64, voff = 1024 + h * 64;

    {   // stage Q (already scaled): thread t -> row t>>1, 32 d
        int q = tid >> 1, dg = (tid & 1) * 32;
        const unsigned short* src = q16 + (tokbase + base + q) * 1536 + qoff + dg;
        uint4 a  = *(const uint4*)src;
        uint4 b4 = *(const uint4*)(src + 8);
        uint4 c4 = *(const uint4*)(src + 16);
        uint4 d4 = *(const uint4*)(src + 24);
        *(uint4*)(Qs + q * 72 + dg)      = a;
        *(uint4*)(Qs + q * 72 + dg + 8)  = b4;
        *(uint4*)(Qs + q * 72 + dg + 16) = c4;
        *(uint4*)(Qs + q * 72 + dg + 24) = d4;
    }
    __syncthreads();
    // Q A-frags: m=l31 (q row), k = kd*16 + l5*8 + j
    short8 aq[4];
#pragma unroll
    for (int kd = 0; kd < 4; ++kd)
        aq[kd] = *(const short8*)(Qs + (wave * 32 + l31) * 72 + kd * 16 + l5 * 8);

    short8 ones;
#pragma unroll
    for (int i = 0; i < 8; ++i) ones[i] = (short)0x3F80;   // bf16 1.0

    f32x16 acc[2], accL;
#pragma unroll
    for (int i = 0; i < 16; ++i) { acc[0][i] = 0.f; acc[1][i] = 0.f; accL[i] = 0.f; }
    __hip_bfloat16* Psw = PsS + wave * (32 * 72);
    unsigned short* Psw16 = (unsigned short*)Psw;

    // prefetch lane roles
    int s_k = tid >> 2, dg_k = (tid & 3) * 16;      // K: 2 uint4 per thread
    int sp = (tid & 31) * 2, dg8 = (tid >> 5) * 8;  // V: 2 uint4 per thread
    uint4 kr0, kr1, va, vb;
    {   // prologue: load tile 0
        const unsigned short* kp = q16 + (tokbase + s_k) * 1536 + koff + dg_k;
        kr0 = *(const uint4*)kp;
        kr1 = *(const uint4*)(kp + 8);
        const unsigned short* vp = q16 + (tokbase + sp) * 1536 + voff + dg8;
        va = *(const uint4*)vp;
        vb = *(const uint4*)(vp + 1536);
    }

    int tmax = 2 * qb + 1;
    for (int tile = 0; tile <= tmax; ++tile) {
        int buf = tile & 1;
        // ---- write prefetched K/V into this tile's buffer
        *(uint4*)(KsS[buf] + s_k * 72 + dg_k)     = kr0;
        *(uint4*)(KsS[buf] + s_k * 72 + dg_k + 8) = kr1;
        {
            unsigned a0[4] = {va.x, va.y, va.z, va.w};
            unsigned b0[4] = {vb.x, vb.y, vb.z, vb.w};
#pragma unroll
            for (int i = 0; i < 4; ++i) {
                unsigned p0 = (a0[i] & 0xffffu) | (b0[i] << 16);
                unsigned p1 = (a0[i] >> 16) | (b0[i] & 0xffff0000u);
                *(unsigned*)(VtS[buf] + (dg8 + 2 * i) * 72 + sp)     = p0;
                *(unsigned*)(VtS[buf] + (dg8 + 2 * i + 1) * 72 + sp) = p1;
            }
        }
        __syncthreads();                      // single barrier per tile
        if (tile < tmax) {                    // prefetch tile+1 under compute
            int s1 = (tile + 1) * 64;
            const unsigned short* kp = q16 + (tokbase + s1 + s_k) * 1536 + koff + dg_k;
            kr0 = *(const uint4*)kp;
            kr1 = *(const uint4*)(kp + 8);
            const unsigned short* vp = q16 + (tokbase + s1 + sp) * 1536 + voff + dg8;
            va = *(const uint4*)vp;
            vb = *(const uint4*)(vp + 1536);
        }
        if (tile == tmax && wave < 2) continue;   // fully masked for waves 0-1
        // ---- QK^T: S[32 q][64 s] per wave
        f32x16 Sc[2];
#pragma unroll
        for (int i = 0; i < 16; ++i) { Sc[0][i] = 0.f; Sc[1][i] = 0.f; }
#pragma unroll
        for (int st = 0; st < 2; ++st)
#pragma unroll
            for (int kd = 0; kd < 4; ++kd) {
                short8 bk = *(const short8*)(KsS[buf] + (st * 32 + l31) * 72 + kd * 16 + l5 * 8);
                Sc[st] = __builtin_amdgcn_mfma_f32_32x32x16_bf16(aq[kd], bk, Sc[st], 0, 0, 0);
            }
        if (tile >= 2 * qb) {                 // diagonal-straddling tiles
            int s0t = tile * 64;
            int qrb = base + wave * 32 + 4 * l5;
#pragma unroll
            for (int st = 0; st < 2; ++st) {
                int sg = s0t + st * 32 + l31;
#pragma unroll
                for (int reg = 0; reg < 16; ++reg) {
                    int qr = qrb + (reg & 3) + 8 * (reg >> 2);
                    if (sg > qr) Sc[st][reg] = -1e30f;
                }
            }
        }
        // ---- p = exp2(score) -> LDS (same-wave region, no barrier)
#pragma unroll
        for (int st = 0; st < 2; ++st)
#pragma unroll
            for (int reg = 0; reg < 16; ++reg) {
                int pr = (reg & 3) + 8 * (reg >> 2) + 4 * l5;
                Psw16[pr * 72 + st * 32 + l31] =
                    truncbf(__builtin_amdgcn_exp2f(Sc[st][reg]));
            }
        // ---- PV: O[32 q][64 d]; l via ones-MFMA
#pragma unroll
        for (int ks = 0; ks < 4; ++ks) {
            short8 ap = *(const short8*)(Psw + l31 * 72 + ks * 16 + l5 * 8);
            accL = __builtin_amdgcn_mfma_f32_32x32x16_bf16(ap, ones, accL, 0, 0, 0);
#pragma unroll
            for (int dt = 0; dt < 2; ++dt) {
                short8 bv = *(const short8*)(VtS[buf] + (dt * 32 + l31) * 72 + ks * 16 + l5 * 8);
                acc[dt] = __builtin_amdgcn_mfma_f32_32x32x16_bf16(ap, bv, acc[dt], 0, 0, 0);
            }
        }
    }
    // ---- epilogue: O[q][d] = acc/l -> o_bf [B*T][512]
#pragma unroll
    for (int reg = 0; reg < 16; ++reg) {
        float rl = 1.0f / accL[reg];
        int qr = base + wave * 32 + (reg & 3) + 8 * (reg >> 2) + 4 * l5;
#pragma unroll
        for (int dt = 0; dt < 2; ++dt)
            ob[(tokbase + qr) * 512 + h * 64 + dt * 32 + l31] =
                __float2bfloat16(acc[dt][reg] * rl);
    }
}

// ---------------------------------------------------------------------------
extern "C" void kernel_launch(void* const* d_in, const int* in_sizes, int n_in,
                              void* d_out, int out_size, void* d_ws, size_t ws_size,
                              hipStream_t stream) {
    const float* x   = (const float*)d_in[0];
    const float* Wq  = (const float*)d_in[1];
    const float* Wk  = (const float*)d_in[2];
    const float* Wv  = (const float*)d_in[3];
    const float* Wo  = (const float*)d_in[4];
    const float* bo  = (const float*)d_in[5];
    const float* W1  = (const float*)d_in[6];
    const float* b1  = (const float*)d_in[7];
    const float* W2  = (const float*)d_in[8];
    const float* b2  = (const float*)d_in[9];
    const float* g1  = (const float*)d_in[10];
    const float* be1 = (const float*)d_in[11];
    const float* g2  = (const float*)d_in[12];
    const float* be2 = (const float*)d_in[13];
    float* out = (float*)d_out;

    // Workspace layout (byte offsets, 16B aligned). Peak ~98 MB.
    char* ws = (char*)d_ws;
    __hip_bfloat16* bqT    = (__hip_bfloat16*)(ws);                  // [1536][512]
    __hip_bfloat16* woT    = (__hip_bfloat16*)(ws + 1572864);        // [512][512]
    __hip_bfloat16* w1T    = (__hip_bfloat16*)(ws + 2097152);        // [4096][512]
    __hip_bfloat16* w2T    = (__hip_bfloat16*)(ws + 6291456);        // [512][4096]
    float*          xn     = (float*)(ws + 10485760);                // [8192][512] fp32 (LN1+bo; Wo RMW -> x2)
    __hip_bfloat16* xn_bf  = (__hip_bfloat16*)(ws + 27262976);       // [8192][512] bf16
    __hip_bfloat16* qkv_bf = (__hip_bfloat16*)(ws + 35651584);       // [8192][1536] bf16
    __hip_bfloat16* o_bf   = (__hip_bfloat16*)(ws + 60817408);       // [8192][512] bf16
    __hip_bfloat16* h_bf   = (__hip_bfloat16*)(ws + 35651584);       // [8192][4096] overlay (qkv/o dead by FFN1)

    // 1. startup: LN1 (+bo fold) and all weight repacks, one dispatch
    startup_kernel<<<Mrows + 1280, 256, 0, stream>>>(
        x, g1, be1, bo, xn, xn_bf, Wq, Wk, Wv, Wo, W1, W2, bqT, woT, w1T, w2T);
    // 2. qkv = xn @ Wqkv  -> bf16   (grid 12x64; q columns pre-scaled)
    mfma_gemm<<<768, 256, 0, stream>>>(
        xn_bf, 512, bqT, 512, qkv_bf, 1536, 512, 12);
    // 3. causal attention (MFMA flash, 32x32x16, 1 barrier/tile) -> o_bf
    attn_mfma<<<Bsz * Hh * (Tt / 128), 256, 0, stream>>>(qkv_bf, o_bf);
    // 4. xn(=x2) += o @ Wo   (128x64 tiles, full K=512, plain RMW, grid 8x64)
    mfma_gemm_n64<<<512, 256, 0, stream>>>(
        o_bf, 512, woT, 512, xn, 512, 512, 8);
    // 5. LN2: out = LN(x2)+b2 (final residual base), xn_bf = LN(x2)
    ln_kernel<<<Mrows, 256, 0, stream>>>(xn, g2, be2, b2, out, xn_bf);
    // 6. h = relu(xn2 @ W1 + b1)  (256x128 tiles, BK=64 pipelined, grid 32x32)
    mfma_gemm256<<<1024, 256, 0, stream>>>(
        xn_bf, 512, w1T, 512, h_bf, HIDs, 512, b1);
    // 7. out += h @ W2  (128x64 tiles, full K=4096, plain RMW, grid 8x64)
    mfma_gemm_n64<<<512, 256, 0, stream>>>(
        h_bf, HIDs, w2T, HIDs, out, 512, HIDs, 8);
}